// Round 9
// baseline (5718.258 us; speedup 1.0000x reference)
//
#include <hip/hip_runtime.h>
#include <hip/hip_bf16.h>

typedef __bf16 bf16;
typedef __bf16 bf16x8 __attribute__((ext_vector_type(8)));
typedef float floatx4 __attribute__((ext_vector_type(4)));
typedef float floatx2 __attribute__((ext_vector_type(2)));
typedef unsigned int uint;
typedef uint uintx4 __attribute__((ext_vector_type(4)));
typedef unsigned long long u64;
typedef u64 u64x2 __attribute__((ext_vector_type(2)));
typedef __attribute__((address_space(1))) void gvoid;
typedef __attribute__((address_space(3))) void lvoid;

#define MFMA16(a, b, c) __builtin_amdgcn_mfma_f32_16x16x32_bf16((a), (b), (c), 0, 0, 0)
#define NB_REC 64
#define NB_GEMM 96
#define FLAG_STRIDE 32
#define HSTR 1040                    // hT row stride (bf16): 2080B, conflict-free
#define CHUNKF (32 * 32 * 3072)      // floats per G ring slot (32 steps)
#define AG __ATOMIC_RELAXED, __HIP_MEMORY_SCOPE_AGENT

static __device__ __forceinline__ floatx2 ldg2(const float* p) {
    union { u64 q; floatx2 f; } u;
    u.q = __hip_atomic_load((const u64*)p, AG);
    return u.f;
}

__global__ void k_cvt(const float* __restrict__ src, bf16* __restrict__ dst, int n) {
    int idx = blockIdx.x * 256 + threadIdx.x;
    if (idx < n) dst[idx] = (bf16)src[idx];
}

// Transpose fp32 (B,T,D) -> (t*32+b, D) bf16; zero flags (3 layers x 64 x
// FLAG_STRIDE) + chunk counters (3x16, within the trailing 64). Zeroed per
// replay => protocol safe against stale state from a previous graph replay.
__global__ void k_prep(const float* __restrict__ inp, bf16* __restrict__ xT,
                       uint* __restrict__ bar) {
    size_t idx = (size_t)blockIdx.x * 256 + threadIdx.x;
    if (blockIdx.x == 0) {
        for (int i = threadIdx.x; i < 3 * NB_REC * FLAG_STRIDE + 64; i += 256)
            bar[i] = 0;
    }
    int d = (int)(idx & 255);
    int t = (int)((idx >> 8) & 511);
    int b = (int)(idx >> 17);
    xT[((size_t)(t * 32 + b) << 8) | d] = (bf16)inp[idx];
}

__global__ void k_movmean(const bf16* __restrict__ xT, bf16* __restrict__ out,
                          int s) {
    size_t idx = (size_t)blockIdx.x * 256 + threadIdx.x;
    int d = (int)(idx & 255);
    int m = (int)(idx >> 8);
    int t = m >> 5, b = m & 31;
    float acc = 0.f;
    for (int i = 0; i < s; ++i)
        acc += (float)xT[(((size_t)(t + i) * 32 + b) << 8) | d];
    out[idx] = (bf16)(acc * (1.f / (float)s));
}

// ---------------------------------------------------------------------------
// Standalone tiled MFMA GEMM (Wout projections). 128x128 tile, BK=64,
// global_load_lds(16B), XOR chunk swizzle.
// ---------------------------------------------------------------------------
__global__ __launch_bounds__(256, 2) void k_gemm(
    const bf16* __restrict__ A1, int lda1, const bf16* __restrict__ W1, int nk1,
    const float* __restrict__ bias1, float* __restrict__ Cf, int ldc, int Mstore) {
    __shared__ bf16 lsA[128 * 64];
    __shared__ bf16 lsW[128 * 64];
    const int tid = threadIdx.x;
    const int lane = tid & 63, w = tid >> 6;
    const int quad = lane >> 4, lr = lane & 15;
    const int wm = w >> 1, wn = w & 1;
    const int m0 = blockIdx.y * 128, n0 = blockIdx.x * 128;

    floatx4 acc[4][4] = {};
    const int lda = lda1, ldw = nk1 * 64;
    for (int kb = 0; kb < nk1; ++kb) {
        const bf16* Ab = A1 + (size_t)m0 * lda + (size_t)kb * 64;
        const bf16* Wb = W1 + (size_t)n0 * ldw + (size_t)kb * 64;
#pragma unroll
        for (int i = 0; i < 4; ++i) {
            int c = (i * 4 + w) * 64 + lane;
            int m = c >> 3, q = c & 7;
            const bf16* g1 = Ab + (size_t)m * lda + ((q ^ (m & 7)) << 3);
            __builtin_amdgcn_global_load_lds((const gvoid*)g1,
                                             (lvoid*)(lsA + (i * 4 + w) * 512), 16, 0, 0);
            const bf16* g2 = Wb + (size_t)m * ldw + ((q ^ (m & 7)) << 3);
            __builtin_amdgcn_global_load_lds((const gvoid*)g2,
                                             (lvoid*)(lsW + (i * 4 + w) * 512), 16, 0, 0);
        }
        __syncthreads();
#pragma unroll
        for (int s = 0; s < 2; ++s) {
            bf16x8 af[4], bfr[4];
#pragma unroll
            for (int i = 0; i < 4; ++i) {
                int kc = s * 4 + quad;
                int m = wm * 64 + i * 16 + lr;
                af[i] = *(const bf16x8*)(lsA + m * 64 + ((kc ^ (m & 7)) << 3));
                int n = wn * 64 + i * 16 + lr;
                bfr[i] = *(const bf16x8*)(lsW + n * 64 + ((kc ^ (n & 7)) << 3));
            }
#pragma unroll
            for (int i = 0; i < 4; ++i)
#pragma unroll
                for (int j = 0; j < 4; ++j)
                    acc[i][j] = MFMA16(af[i], bfr[j], acc[i][j]);
        }
        __syncthreads();
    }
#pragma unroll
    for (int j = 0; j < 4; ++j) {
        int col = n0 + wn * 64 + j * 16 + lr;
        float bs = bias1 ? bias1[col] : 0.f;
#pragma unroll
        for (int i = 0; i < 4; ++i) {
            int rowb = m0 + wm * 64 + i * 16 + quad * 4;
#pragma unroll
            for (int r = 0; r < 4; ++r) {
                int row = rowb + r;
                if (row < Mstore) Cf[(size_t)row * ldc + col] = acc[i][j][r] + bs;
            }
        }
    }
}

// ---------------------------------------------------------------------------
// Fused per-layer kernel: 160 blocks x 384 threads, 96KB LDS (1 block/CU).
//   Blocks 0..63   : round-7 persistent GRU recurrence (breg Whh from fp32,
//                    padded hT, drained 1KB publish -> flag -> deferred
//                    traffic -> poll) + chunk gate every 32 steps.
//   Blocks 64..159 : GEMM workers, XCD-GROUPED tile assignment: group
//                    x = (blk-64)&7 (heuristic blk%8 ~ XCD) owns col panels
//                    [3x, 3x+3) for all 8 row panels -> per-XCD W working
//                    set ~1MB stays L2-resident across chunks (was 7.7MB,
//                    thrashing to L3 every chunk = the round-8 interference).
//                    sc1 G stores -> syncthreads drain -> ONE atomicAdd.
//                    Backpressure: chunk c>=2 waits rec flags >= (c-1)*32.
// ---------------------------------------------------------------------------
__global__ __launch_bounds__(384, 1) void k_fused(
    const bf16* __restrict__ A1, int lda1, const bf16* __restrict__ W1, int nk1,
    const bf16* __restrict__ A2, int lda2, const bf16* __restrict__ W2, int nk2,
    const float* __restrict__ bias1, const float* __restrict__ bias2,
    float* __restrict__ G, const float* __restrict__ Whh,
    const float* __restrict__ bhh, bf16* __restrict__ outs,
    bf16* __restrict__ h01, float* __restrict__ hid_out,
    uint* __restrict__ bar, uint* __restrict__ cdone, int T) {

    __shared__ __attribute__((aligned(16))) char smem[98304];
    const int tid = threadIdx.x, blk = blockIdx.x;
    const int lane = tid & 63, w = tid >> 6;
    const int quad = lane >> 4, lr = lane & 15;

    if (blk >= NB_REC) {
        // ------------------------- GEMM worker role -----------------------
        bf16* lsA = (bf16*)smem;
        bf16* lsW = (bf16*)(smem + 16384);
        const int wm = w >> 1, wn = w & 1;
        const int g = blk - NB_REC;
        const int xg = g & 7;    // XCD group (blk%8 heuristic)
        const int ig = g >> 3;   // 0..11 within group
        const int Mstore = T * 32;
        const int nc = (T + 31) >> 5;
        const bf16* As[2] = {A1, A2};
        const bf16* Ws[2] = {W1, W2};
        const int ldas[2] = {lda1, lda2};
        const int nks[2] = {nk1, nk2};
        for (int c = 0; c < nc; ++c) {
            if (c >= 2) {  // ring slot (c&1) free once rec consumed chunk c-2
                if (tid < 64) {
                    const uint* fp = bar + (uint)tid * FLAG_STRIDE;
                    const uint need = (uint)((c - 1) * 32);
                    while (__hip_atomic_load(fp, AG) < need)
                        __builtin_amdgcn_s_sleep(2);
                }
                __syncthreads();
            }
            float* Gs = G + (size_t)(c & 1) * CHUNKF;
#pragma unroll 1
            for (int half = 0; half < 2; ++half) {
                int lt = ig * 2 + half;         // 0..23 within XCD group
                int by = lt & 7;                // row panel 0..7
                int bx = xg * 3 + (lt >> 3);    // col panel: fixed 3 per group
                int m0g = c * 1024 + by * 128;
                int n0 = bx * 128;
                floatx4 acc[4][4] = {};
                for (int ph = 0; ph < 2; ++ph) {
                    const int nk = nks[ph];
                    const bf16* A = As[ph];
                    const bf16* Wp = Ws[ph];
                    const int lda = ldas[ph];
                    const int ldw = nk * 64;
                    for (int kb = 0; kb < nk; ++kb) {
                        const bf16* Ab = A + (size_t)m0g * lda + (size_t)kb * 64;
                        const bf16* Wb = Wp + (size_t)n0 * ldw + (size_t)kb * 64;
                        if (w < 4) {
#pragma unroll
                            for (int i = 0; i < 4; ++i) {
                                int cc = (i * 4 + w) * 64 + lane;
                                int m = cc >> 3, q = cc & 7;
                                const bf16* g1 = Ab + (size_t)m * lda + ((q ^ (m & 7)) << 3);
                                __builtin_amdgcn_global_load_lds((const gvoid*)g1,
                                                                 (lvoid*)(lsA + (i * 4 + w) * 512), 16, 0, 0);
                                const bf16* g2 = Wb + (size_t)m * ldw + ((q ^ (m & 7)) << 3);
                                __builtin_amdgcn_global_load_lds((const gvoid*)g2,
                                                                 (lvoid*)(lsW + (i * 4 + w) * 512), 16, 0, 0);
                            }
                        }
                        __syncthreads();
                        if (w < 4) {
#pragma unroll
                            for (int s = 0; s < 2; ++s) {
                                bf16x8 af[4], bfr[4];
#pragma unroll
                                for (int i = 0; i < 4; ++i) {
                                    int kc = s * 4 + quad;
                                    int m = wm * 64 + i * 16 + lr;
                                    af[i] = *(const bf16x8*)(lsA + m * 64 + ((kc ^ (m & 7)) << 3));
                                    int n = wn * 64 + i * 16 + lr;
                                    bfr[i] = *(const bf16x8*)(lsW + n * 64 + ((kc ^ (n & 7)) << 3));
                                }
#pragma unroll
                                for (int i = 0; i < 4; ++i)
#pragma unroll
                                    for (int j = 0; j < 4; ++j)
                                        acc[i][j] = MFMA16(af[i], bfr[j], acc[i][j]);
                            }
                        }
                        __syncthreads();
                    }
                }
                if (w < 4) {
#pragma unroll
                    for (int j = 0; j < 4; ++j) {
                        int col = n0 + wn * 64 + j * 16 + lr;
                        float bs = bias1[col] + bias2[col];
#pragma unroll
                        for (int i = 0; i < 4; ++i) {
                            int rowb = m0g + wm * 64 + i * 16 + quad * 4;
#pragma unroll
                            for (int r = 0; r < 4; ++r) {
                                int row = rowb + r;
                                if (row < Mstore) {
                                    float v = acc[i][j][r] + bs;
                                    __hip_atomic_store(
                                        (uint*)(Gs + (size_t)(row - c * 1024) * 3072 + col),
                                        __float_as_uint(v), AG);
                                }
                            }
                        }
                    }
                }
            }
            __syncthreads();  // drains this block's sc1 G stores
            if (tid == 0) atomicAdd(cdone + c, 1u);  // ONE signal per block
        }
        return;
    }

    // ----------------------------- REC role (round-7) ---------------------
    bf16* hT = (bf16*)smem;              // 32 x HSTR bf16, 66,560B
    float* gh = (float*)(smem + 66560);  // 96 x 17 fp32, 6,528B
    const int mi = (w >= 3) ? 1 : 0, ni = w - mi * 3;

    // Whh B-fragments -> registers, one-time load DIRECT from fp32 (RNE cast
    // identical to the old k_cvt path; deletes the wHh cvt launch per layer).
    const float* wrow = Whh + ((size_t)ni * 1024 + blk * 16 + lr) * 1024 + quad * 8;
    bf16x8 breg[32];
#pragma unroll
    for (int kt = 0; kt < 32; ++kt) {
        const floatx4* p = (const floatx4*)(wrow + kt * 32);
        floatx4 lo = p[0], hi = p[1];
        bf16x8 b;
        b[0] = (bf16)lo.x; b[1] = (bf16)lo.y; b[2] = (bf16)lo.z; b[3] = (bf16)lo.w;
        b[4] = (bf16)hi.x; b[5] = (bf16)hi.y; b[6] = (bf16)hi.z; b[7] = (bf16)hi.w;
        breg[kt] = b;
    }

    const int eb = tid >> 3;
    const int ec = (tid & 7) * 2;
    const int ecg = blk * 16 + ec;

    float bhr0 = 0.f, bhr1 = 0.f, bhi0 = 0.f, bhi1 = 0.f, bhn0 = 0.f, bhn1 = 0.f;
    if (tid < 256) {
        bhr0 = bhh[ecg];        bhr1 = bhh[ecg + 1];
        bhi0 = bhh[1024 + ecg]; bhi1 = bhh[1024 + ecg + 1];
        bhn0 = bhh[2048 + ecg]; bhn1 = bhh[2048 + ecg + 1];
    }
    float hreg0 = 0.f, hreg1 = 0.f;  // h0 = 0
    floatx2 pAr = {0.f, 0.f}, pAi = {0.f, 0.f}, pAn = {0.f, 0.f};
    floatx2 pBr = {0.f, 0.f}, pBi = {0.f, 0.f}, pBn = {0.f, 0.f};
    uint* myflag = bar + (uint)blk * FLAG_STRIDE;

    for (int t = 0; t < T; ++t) {
        // Chunk gate every 32 steps: wait for G chunk, fresh pA from ring.
        if ((t & 31) == 0) {
            const uint* cd = cdone + (t >> 5);
            if (tid < 64) {
                while (__hip_atomic_load(cd, AG) < (uint)NB_GEMM)
                    __builtin_amdgcn_s_sleep(1);
            }
            __syncthreads();
            if (tid < 256) {
                const float* Grow = G + (size_t)((t >> 5) & 1) * CHUNKF
                                      + ((size_t)(t & 31) * 32 + eb) * 3072 + ecg;
                pAr = ldg2(Grow);
                pAi = ldg2(Grow + 1024);
                pAn = ldg2(Grow + 2048);
            }
        }

        // --- Stage h_t -> LDS (padded HSTR layout). t=0: zeros. ------------
        if (t == 0) {
            for (int i = tid; i < 4096; i += 384) {
                int row = i >> 7, q = i & 127;
                uintx4 z = {0u, 0u, 0u, 0u};
                *(uintx4*)(hT + row * HSTR + q * 8) = z;
            }
        } else {
            const bf16* hb = h01 + (size_t)(t & 1) * (32 * 1024);
            u64 s0[11], s1[11];
#pragma unroll
            for (int r = 0; r < 11; ++r) {
                int ci = tid + r * 384;
                if (r < 10 || ci < 4096) {
                    const u64* src = (const u64*)(hb + (size_t)ci * 8);
                    s0[r] = __hip_atomic_load(src, AG);
                    s1[r] = __hip_atomic_load(src + 1, AG);
                }
            }
#pragma unroll
            for (int r = 0; r < 11; ++r) {
                int ci = tid + r * 384;
                if (r < 10 || ci < 4096) {
                    int row = ci >> 7, q = ci & 127;
                    u64x2 v;
                    v.x = s0[r];
                    v.y = s1[r];
                    *(u64x2*)(hT + row * HSTR + q * 8) = v;
                }
            }
        }
        __syncthreads();  // S1: hT staged

        // --- MFMA: A from LDS, B from registers ---------------------------
        floatx4 acc0 = {0.f, 0.f, 0.f, 0.f}, acc1 = {0.f, 0.f, 0.f, 0.f};
        const bf16* aB = hT + (mi * 16 + lr) * HSTR + quad * 8;
#pragma unroll
        for (int kt = 0; kt < 32; kt += 2) {
            bf16x8 a0 = *(const bf16x8*)(aB + kt * 32);
            acc0 = MFMA16(a0, breg[kt], acc0);
            bf16x8 a1 = *(const bf16x8*)(aB + kt * 32 + 32);
            acc1 = MFMA16(a1, breg[kt + 1], acc1);
        }
        floatx4 acc = acc0 + acc1;
#pragma unroll
        for (int r = 0; r < 4; ++r)
            gh[(ni * 32 + mi * 16 + quad * 4 + r) * 17 + lr] = acc[r];
        __syncthreads();  // S2: gh ready

        uint pku = 0u;
        if (tid < 256) {
            float ghr0 = gh[eb * 17 + ec]            + bhr0;
            float ghr1 = gh[eb * 17 + ec + 1]        + bhr1;
            float ghi0 = gh[(32 + eb) * 17 + ec]     + bhi0;
            float ghi1 = gh[(32 + eb) * 17 + ec + 1] + bhi1;
            float ghn0 = gh[(64 + eb) * 17 + ec]     + bhn0;
            float ghn1 = gh[(64 + eb) * 17 + ec + 1] + bhn1;
            float rg0 = 1.f / (1.f + __expf(-(pAr.x + ghr0)));
            float rg1 = 1.f / (1.f + __expf(-(pAr.y + ghr1)));
            float ig0 = 1.f / (1.f + __expf(-(pAi.x + ghi0)));
            float ig1 = 1.f / (1.f + __expf(-(pAi.y + ghi1)));
            float pre0 = pAn.x + rg0 * ghn0;
            float pre1 = pAn.y + rg1 * ghn1;
            float e20 = __expf(2.f * pre0);
            float e21 = __expf(2.f * pre1);
            float ng0 = 1.f - 2.f / (e20 + 1.f);  // tanh(pre)
            float ng1 = 1.f - 2.f / (e21 + 1.f);
            hreg0 = ng0 + ig0 * (hreg0 - ng0);
            hreg1 = ng1 + ig1 * (hreg1 - ng1);
            union { bf16 h[2]; uint u; } pk;
            pk.h[0] = (bf16)hreg0;
            pk.h[1] = (bf16)hreg1;
            pku = pk.u;
            // Publish h_{t+1} (sc1): the ONLY memory op the next sync drains.
            __hip_atomic_store((uint*)(h01 + (size_t)((t + 1) & 1) * (32 * 1024)
                                       + (size_t)eb * 1024 + ecg), pku, AG);
        }
        __syncthreads();  // S3: drains just the 1KB h publish

        if (tid == 0)
            __hip_atomic_store(myflag, (uint)(t + 1), AG);

        // Deferred traffic drains under the poll window.
        if (tid < 256) {
            if (t + 1 < T && ((t + 1) & 31) != 0) {
                const float* Grow = G + (size_t)((t >> 5) & 1) * CHUNKF
                                      + ((size_t)((t + 1) & 31) * 32 + eb) * 3072 + ecg;
                pBr = ldg2(Grow);
                pBi = ldg2(Grow + 1024);
                pBn = ldg2(Grow + 2048);
            }
            *(uint*)(outs + ((size_t)t * 32 + eb) * 1024 + ecg) = pku;
        }
        if (t + 1 < T && tid < NB_REC) {
            const uint* fp = bar + (uint)tid * FLAG_STRIDE;
            while (__hip_atomic_load(fp, AG) < (uint)(t + 1))
                __builtin_amdgcn_s_sleep(1);
        }
        __syncthreads();  // S4

        pAr = pBr; pAi = pBi; pAn = pBn;
    }

    if (tid < 256) {
        floatx2 h;
        h.x = hreg0;
        h.y = hreg1;
        *(floatx2*)(hid_out + (size_t)eb * 1024 + ecg) = h;
    }
}

// ---------------------------------------------------------------------------
extern "C" void kernel_launch(void* const* d_in, const int* in_sizes, int n_in,
                              void* d_out, int out_size, void* d_ws, size_t ws_size,
                              hipStream_t stream) {
    const float* inp  = (const float*)d_in[0];
    const float* Wxh0 = (const float*)d_in[1];
    const float* bxh0 = (const float*)d_in[2];
    const float* Whh0 = (const float*)d_in[3];
    const float* bhh0 = (const float*)d_in[4];
    const float* Wnh0 = (const float*)d_in[5];
    const float* bnh0 = (const float*)d_in[6];
    const float* Wxh1 = (const float*)d_in[7];
    const float* bxh1 = (const float*)d_in[8];
    const float* Whh1 = (const float*)d_in[9];
    const float* bhh1 = (const float*)d_in[10];
    const float* Wnh1 = (const float*)d_in[11];
    const float* bnh1 = (const float*)d_in[12];
    const float* Wxh2 = (const float*)d_in[13];
    const float* bxh2 = (const float*)d_in[14];
    const float* Whh2 = (const float*)d_in[15];
    const float* bhh2 = (const float*)d_in[16];
    const float* Wnh2 = (const float*)d_in[17];
    const float* bnh2 = (const float*)d_in[18];
    const float* Wout = (const float*)d_in[19];
    const float* bout = (const float*)d_in[20];
    float* out = (float*)d_out;  // reference output dtype is float32

    char* ws = (char*)d_ws;
    size_t o = 0;
    auto take = [&](size_t bytes) {
        o = (o + 255) & ~(size_t)255;
        char* p = ws + o;
        o += bytes;
        return p;
    };
    const size_t RP = 16512;  // row padding: covers GEMM A-tile overread
    bf16* xT    = (bf16*)take(RP * 256 * 2);
    bf16* ms1   = (bf16*)take(RP * 256 * 2);
    bf16* ms2   = (bf16*)take(RP * 256 * 2);
    bf16* outs0 = (bf16*)take(RP * 1024 * 2);
    bf16* outs1 = (bf16*)take(RP * 1024 * 2);
    bf16* outs2 = outs0;  // alias: outs0 dead after proj0 (launched first)
    bf16* h01   = (bf16*)take((size_t)2 * 32 * 1024 * 2);
    uint* bar   = (uint*)take((size_t)(3 * NB_REC * FLAG_STRIDE + 64) * 4);
    bf16* wXh = (bf16*)take((size_t)3072 * 1024 * 2);
    bf16* wNh = (bf16*)take((size_t)3072 * 256 * 2);
    bf16* wOut = (bf16*)take((size_t)256 * 1024 * 2);
    float* G = (float*)take((size_t)2 * CHUNKF * 4);  // 2-slot ring (25.2MB)
    (void)in_sizes; (void)n_in; (void)out_size; (void)ws_size;

    const size_t o0 = 0, o1 = (size_t)512 * 32 * 256, o2 = o1 + (size_t)511 * 32 * 256;
    const size_t ohid = o2 + (size_t)509 * 32 * 256;

    auto cvt = [&](const float* s, bf16* d, int n) {
        k_cvt<<<(n + 255) / 256, 256, 0, stream>>>(s, d, n);
    };
    cvt(Wout, wOut, 256 * 1024);
    k_prep<<<16384, 256, 0, stream>>>(inp, xT, bar);
    k_movmean<<<511 * 32, 256, 0, stream>>>(xT, ms1, 2);
    k_movmean<<<509 * 32, 256, 0, stream>>>(xT, ms2, 4);

    auto run_layer = [&](const bf16* xs, int ldx, const float* Wxh, int nkx,
                         const bf16* ms, const float* Wnh,
                         const float* bxh, const float* bnh,
                         const float* Whh, const float* bhh,
                         bf16* outs, float* hid, int T, int layer) {
        cvt(Wxh, wXh, 3072 * nkx * 64);
        cvt(Wnh, wNh, 3072 * 256);
        uint* barL = bar + (size_t)NB_REC * FLAG_STRIDE * layer;
        uint* cdL  = bar + 3 * NB_REC * FLAG_STRIDE + 16 * layer;
        k_fused<<<NB_REC + NB_GEMM, 384, 0, stream>>>(
            xs, ldx, wXh, nkx, ms, 256, wNh, 4, bxh, bnh, G,
            Whh, bhh, outs, h01, hid, barL, cdL, T);
    };

    // Layer 0 (ms0 == x): G = x@Wxh0^T + x@Wnh0^T + bxh0 + bnh0
    run_layer(xT, 256, Wxh0, 4, xT, Wnh0, bxh0, bnh0, Whh0, bhh0,
              outs0, out + ohid, 512, 0);
    // Layer 1: xs = outs0[1:], ms = ms1
    run_layer(outs0 + (size_t)32 * 1024, 1024, Wxh1, 16, ms1, Wnh1,
              bxh1, bnh1, Whh1, bhh1, outs1, out + ohid + 32768, 511, 1);
    // Projection of layer-0 outs BEFORE layer 2 overwrites the aliased buffer.
    k_gemm<<<dim3(2, 128), 256, 0, stream>>>(outs0, 1024, wOut, 16,
                                             bout, out + o0, 256, 16384);
    // Layer 2: xs = outs1[2:], ms = ms2; outs2 aliases outs0.
    run_layer(outs1 + (size_t)64 * 1024, 1024, Wxh2, 16, ms2, Wnh2,
              bxh2, bnh2, Whh2, bhh2, outs2, out + ohid + 65536, 509, 2);

    k_gemm<<<dim3(2, 128), 256, 0, stream>>>(outs1, 1024, wOut, 16,
                                             bout, out + o1, 256, 16352);
    k_gemm<<<dim3(2, 128), 256, 0, stream>>>(outs2, 1024, wOut, 16,
                                             bout, out + o2, 256, 16288);
}

// Round 10
// 2869.649 us; speedup vs baseline: 1.9927x; 1.9927x over previous
//
#include <hip/hip_runtime.h>
#include <hip/hip_bf16.h>

typedef __bf16 bf16;
typedef __bf16 bf16x8 __attribute__((ext_vector_type(8)));
typedef float floatx4 __attribute__((ext_vector_type(4)));
typedef float floatx2 __attribute__((ext_vector_type(2)));
typedef unsigned int uint;
typedef uint uintx4 __attribute__((ext_vector_type(4)));
typedef unsigned long long u64;
typedef u64 u64x2 __attribute__((ext_vector_type(2)));
typedef __attribute__((address_space(1))) void gvoid;
typedef __attribute__((address_space(3))) void lvoid;

#define MFMA16(a, b, c) __builtin_amdgcn_mfma_f32_16x16x32_bf16((a), (b), (c), 0, 0, 0)
#define NB_REC 64
#define NB_W 64                       // mega: worker blocks
#define FLAG_STRIDE 32
#define HSTR 1040                     // hT row stride (bf16): conflict-free
#define CHUNKF (32 * 32 * 3072)       // floats per G ring slot (32 steps)
#define AG __ATOMIC_RELAXED, __HIP_MEMORY_SCOPE_AGENT

struct MegaArgs {
    const bf16* xs[3];  int lda[3];
    const bf16* wXh[3]; int nkx[3];
    const bf16* ms[3];
    const bf16* wNh[3];
    const float* bxh[3]; const float* bnh[3];
    const float* Whh[3]; const float* bhh[3];
    bf16* outs[3];
    float* hid[3];
    float* G[3];
    uint* bar[3];
    uint* cdone[3];
    bf16* h01[3];
    int T[3];
};

static __device__ __forceinline__ floatx2 ldg2(const float* p) {
    union { u64 q; floatx2 f; } u;
    u.q = __hip_atomic_load((const u64*)p, AG);
    return u.f;
}

__global__ void k_cvt(const float* __restrict__ src, bf16* __restrict__ dst, int n) {
    int idx = blockIdx.x * 256 + threadIdx.x;
    if (idx < n) dst[idx] = (bf16)src[idx];
}

// Transpose fp32 (B,T,D) -> (t*32+b, D) bf16; zero flags (3 x 64 x
// FLAG_STRIDE) + chunk counters (3 x 16). Zeroed per graph replay.
__global__ void k_prep(const float* __restrict__ inp, bf16* __restrict__ xT,
                       uint* __restrict__ bar) {
    size_t idx = (size_t)blockIdx.x * 256 + threadIdx.x;
    if (blockIdx.x == 0) {
        for (int i = threadIdx.x; i < 3 * NB_REC * FLAG_STRIDE + 64; i += 256)
            bar[i] = 0;
    }
    int d = (int)(idx & 255);
    int t = (int)((idx >> 8) & 511);
    int b = (int)(idx >> 17);
    xT[((size_t)(t * 32 + b) << 8) | d] = (bf16)inp[idx];
}

__global__ void k_movmean(const bf16* __restrict__ xT, bf16* __restrict__ out,
                          int s) {
    size_t idx = (size_t)blockIdx.x * 256 + threadIdx.x;
    int d = (int)(idx & 255);
    int m = (int)(idx >> 8);
    int t = m >> 5, b = m & 31;
    float acc = 0.f;
    for (int i = 0; i < s; ++i)
        acc += (float)xT[(((size_t)(t + i) * 32 + b) << 8) | d];
    out[idx] = (bf16)(acc * (1.f / (float)s));
}

// ---------------------------------------------------------------------------
// Tiled MFMA GEMM, 128x128 tile, BK=64 (round-7, proven). Used for the Wout
// projections and as the gate GEMM in the serial fallback path.
// ---------------------------------------------------------------------------
__global__ __launch_bounds__(256, 2) void k_gemm(
    const bf16* __restrict__ A1, int lda1, const bf16* __restrict__ W1, int nk1,
    const bf16* __restrict__ A2, int lda2, const bf16* __restrict__ W2, int nk2,
    const float* __restrict__ bias1, const float* __restrict__ bias2,
    float* __restrict__ Cf, bf16* __restrict__ Cb, int ldc, int Mstore) {
    __shared__ bf16 lsA[128 * 64];
    __shared__ bf16 lsW[128 * 64];
    const int tid = threadIdx.x;
    const int lane = tid & 63, w = tid >> 6;
    const int quad = lane >> 4, lr = lane & 15;
    const int wm = w >> 1, wn = w & 1;
    const int m0 = blockIdx.y * 128, n0 = blockIdx.x * 128;

    floatx4 acc[4][4] = {};
    const bf16* As[2] = {A1, A2};
    const bf16* Ws[2] = {W1, W2};
    const int ldas[2] = {lda1, lda2};
    const int nks[2] = {nk1, nk2};

    for (int ph = 0; ph < 2; ++ph) {
        const int nk = nks[ph];
        if (nk == 0) continue;
        const bf16* A = As[ph];
        const bf16* Wp = Ws[ph];
        const int lda = ldas[ph];
        const int ldw = nk * 64;
        for (int kb = 0; kb < nk; ++kb) {
            const bf16* Ab = A + (size_t)m0 * lda + (size_t)kb * 64;
            const bf16* Wb = Wp + (size_t)n0 * ldw + (size_t)kb * 64;
#pragma unroll
            for (int i = 0; i < 4; ++i) {
                int c = (i * 4 + w) * 64 + lane;
                int m = c >> 3, q = c & 7;
                const bf16* g1 = Ab + (size_t)m * lda + ((q ^ (m & 7)) << 3);
                __builtin_amdgcn_global_load_lds((const gvoid*)g1,
                                                 (lvoid*)(lsA + (i * 4 + w) * 512), 16, 0, 0);
                const bf16* g2 = Wb + (size_t)m * ldw + ((q ^ (m & 7)) << 3);
                __builtin_amdgcn_global_load_lds((const gvoid*)g2,
                                                 (lvoid*)(lsW + (i * 4 + w) * 512), 16, 0, 0);
            }
            __syncthreads();
#pragma unroll
            for (int s = 0; s < 2; ++s) {
                bf16x8 af[4], bfr[4];
#pragma unroll
                for (int i = 0; i < 4; ++i) {
                    int kc = s * 4 + quad;
                    int m = wm * 64 + i * 16 + lr;
                    af[i] = *(const bf16x8*)(lsA + m * 64 + ((kc ^ (m & 7)) << 3));
                    int n = wn * 64 + i * 16 + lr;
                    bfr[i] = *(const bf16x8*)(lsW + n * 64 + ((kc ^ (n & 7)) << 3));
                }
#pragma unroll
                for (int i = 0; i < 4; ++i)
#pragma unroll
                    for (int j = 0; j < 4; ++j)
                        acc[i][j] = MFMA16(af[i], bfr[j], acc[i][j]);
            }
            __syncthreads();
        }
    }
#pragma unroll
    for (int j = 0; j < 4; ++j) {
        int col = n0 + wn * 64 + j * 16 + lr;
        float bs = 0.f;
        if (bias1) bs += bias1[col];
        if (bias2) bs += bias2[col];
#pragma unroll
        for (int i = 0; i < 4; ++i) {
            int rowb = m0 + wm * 64 + i * 16 + quad * 4;
#pragma unroll
            for (int r = 0; r < 4; ++r) {
                int row = rowb + r;
                if (row < Mstore) {
                    float v = acc[i][j][r] + bs;
                    if (Cf) Cf[(size_t)row * ldc + col] = v;
                    else    Cb[(size_t)row * ldc + col] = (bf16)v;
                }
            }
        }
    }
}

// ---------------------------------------------------------------------------
// Serial-fallback persistent GRU recurrence (round-7, proven; breg loaded
// directly from fp32 Whh as proven inside round-9's fused rec).
// ---------------------------------------------------------------------------
__global__ __launch_bounds__(384, 1) void k_rec(
    const float* __restrict__ G, const float* __restrict__ Whh,
    const float* __restrict__ bhh, bf16* __restrict__ outs,
    bf16* __restrict__ h01, float* __restrict__ hf,
    float* __restrict__ hid_out, uint* __restrict__ bar,
    int T, int init, int final_, uint tgt0) {
    const int tid = threadIdx.x, blk = blockIdx.x;
    const int lane = tid & 63, w = tid >> 6;
    const int quad = lane >> 4, lr = lane & 15;
    const int mi = (w >= 3) ? 1 : 0, ni = w - mi * 3;

    __shared__ __attribute__((aligned(16))) char smem[73088];
    bf16* hT = (bf16*)smem;
    float* gh = (float*)(smem + 66560);

    const float* wrow = Whh + ((size_t)ni * 1024 + blk * 16 + lr) * 1024 + quad * 8;
    bf16x8 breg[32];
#pragma unroll
    for (int kt = 0; kt < 32; ++kt) {
        const floatx4* p = (const floatx4*)(wrow + kt * 32);
        floatx4 lo = p[0], hi = p[1];
        bf16x8 b;
        b[0] = (bf16)lo.x; b[1] = (bf16)lo.y; b[2] = (bf16)lo.z; b[3] = (bf16)lo.w;
        b[4] = (bf16)hi.x; b[5] = (bf16)hi.y; b[6] = (bf16)hi.z; b[7] = (bf16)hi.w;
        breg[kt] = b;
    }

    const int eb = tid >> 3;
    const int ec = (tid & 7) * 2;
    const int ecg = blk * 16 + ec;

    float bhr0 = 0.f, bhr1 = 0.f, bhi0 = 0.f, bhi1 = 0.f, bhn0 = 0.f, bhn1 = 0.f;
    float hreg0 = 0.f, hreg1 = 0.f;
    if (tid < 256) {
        bhr0 = bhh[ecg];        bhr1 = bhh[ecg + 1];
        bhi0 = bhh[1024 + ecg]; bhi1 = bhh[1024 + ecg + 1];
        bhn0 = bhh[2048 + ecg]; bhn1 = bhh[2048 + ecg + 1];
        if (!init) {
            floatx2 h = *(const floatx2*)(hf + (size_t)eb * 1024 + ecg);
            hreg0 = h.x;
            hreg1 = h.y;
        }
        union { bf16 h[2]; uint u; } pk;
        pk.h[0] = (bf16)hreg0;
        pk.h[1] = (bf16)hreg1;
        __hip_atomic_store((uint*)(h01 + (size_t)eb * 1024 + ecg), pk.u, AG);
    }

    floatx2 pAr, pAi, pAn, pBr, pBi, pBn;
    if (tid < 256) {
        const float* Grow = G + (size_t)eb * 3072 + ecg;
        pAr = *(const floatx2*)(Grow);
        pAi = *(const floatx2*)(Grow + 1024);
        pAn = *(const floatx2*)(Grow + 2048);
    }

    uint* myflag = bar + (uint)blk * FLAG_STRIDE;

    __syncthreads();
    if (tid == 0) __hip_atomic_store(myflag, tgt0, AG);
    if (tid < NB_REC) {
        const uint* fp = bar + (uint)tid * FLAG_STRIDE;
        while (__hip_atomic_load(fp, AG) < tgt0) __builtin_amdgcn_s_sleep(1);
    }
    __syncthreads();

    for (int t = 0; t < T; ++t) {
        const bf16* hb = h01 + (size_t)(t & 1) * (32 * 1024);
        bf16* hn = h01 + (size_t)((t + 1) & 1) * (32 * 1024);

        u64 s0[11], s1[11];
#pragma unroll
        for (int r = 0; r < 11; ++r) {
            int ci = tid + r * 384;
            if (r < 10 || ci < 4096) {
                const u64* src = (const u64*)(hb + (size_t)ci * 8);
                s0[r] = __hip_atomic_load(src, AG);
                s1[r] = __hip_atomic_load(src + 1, AG);
            }
        }
#pragma unroll
        for (int r = 0; r < 11; ++r) {
            int ci = tid + r * 384;
            if (r < 10 || ci < 4096) {
                int row = ci >> 7, q = ci & 127;
                u64x2 v; v.x = s0[r]; v.y = s1[r];
                *(u64x2*)(hT + row * HSTR + q * 8) = v;
            }
        }
        __syncthreads();

        floatx4 acc0 = {0.f, 0.f, 0.f, 0.f}, acc1 = {0.f, 0.f, 0.f, 0.f};
        const bf16* aB = hT + (mi * 16 + lr) * HSTR + quad * 8;
#pragma unroll
        for (int kt = 0; kt < 32; kt += 2) {
            bf16x8 a0 = *(const bf16x8*)(aB + kt * 32);
            acc0 = MFMA16(a0, breg[kt], acc0);
            bf16x8 a1 = *(const bf16x8*)(aB + kt * 32 + 32);
            acc1 = MFMA16(a1, breg[kt + 1], acc1);
        }
        floatx4 acc = acc0 + acc1;
#pragma unroll
        for (int r = 0; r < 4; ++r)
            gh[(ni * 32 + mi * 16 + quad * 4 + r) * 17 + lr] = acc[r];
        __syncthreads();

        uint pku = 0u;
        if (tid < 256) {
            float ghr0 = gh[eb * 17 + ec]            + bhr0;
            float ghr1 = gh[eb * 17 + ec + 1]        + bhr1;
            float ghi0 = gh[(32 + eb) * 17 + ec]     + bhi0;
            float ghi1 = gh[(32 + eb) * 17 + ec + 1] + bhi1;
            float ghn0 = gh[(64 + eb) * 17 + ec]     + bhn0;
            float ghn1 = gh[(64 + eb) * 17 + ec + 1] + bhn1;
            float rg0 = 1.f / (1.f + __expf(-(pAr.x + ghr0)));
            float rg1 = 1.f / (1.f + __expf(-(pAr.y + ghr1)));
            float ig0 = 1.f / (1.f + __expf(-(pAi.x + ghi0)));
            float ig1 = 1.f / (1.f + __expf(-(pAi.y + ghi1)));
            float pre0 = pAn.x + rg0 * ghn0;
            float pre1 = pAn.y + rg1 * ghn1;
            float e20 = __expf(2.f * pre0);
            float e21 = __expf(2.f * pre1);
            float ng0 = 1.f - 2.f / (e20 + 1.f);
            float ng1 = 1.f - 2.f / (e21 + 1.f);
            hreg0 = ng0 + ig0 * (hreg0 - ng0);
            hreg1 = ng1 + ig1 * (hreg1 - ng1);
            union { bf16 h[2]; uint u; } pk;
            pk.h[0] = (bf16)hreg0;
            pk.h[1] = (bf16)hreg1;
            pku = pk.u;
            __hip_atomic_store((uint*)(hn + (size_t)eb * 1024 + ecg), pku, AG);
        }
        __syncthreads();

        uint tgt = tgt0 + 1 + (uint)t;
        if (tid == 0) __hip_atomic_store(myflag, tgt, AG);

        if (tid < 256) {
            if (t + 1 < T) {
                const float* Grow = G + ((size_t)(t + 1) * 32 + eb) * 3072 + ecg;
                pBr = *(const floatx2*)(Grow);
                pBi = *(const floatx2*)(Grow + 1024);
                pBn = *(const floatx2*)(Grow + 2048);
            }
            *(uint*)(outs + ((size_t)t * 32 + eb) * 1024 + ecg) = pku;
        }
        if (t + 1 < T && tid < NB_REC) {
            const uint* fp = bar + (uint)tid * FLAG_STRIDE;
            while (__hip_atomic_load(fp, AG) < tgt) __builtin_amdgcn_s_sleep(1);
        }
        __syncthreads();

        pAr = pBr; pAi = pBi; pAn = pBn;
    }

    if (tid < 256) {
        floatx2 h; h.x = hreg0; h.y = hreg1;
        *(floatx2*)(hf + (size_t)eb * 1024 + ecg) = h;
        if (final_) *(floatx2*)(hid_out + (size_t)eb * 1024 + ecg) = h;
    }
}

// ---------------------------------------------------------------------------
// MEGA kernel: all 3 layers pipelined. 256 blocks x 384 threads, 96KB LDS.
//   Blocks 0..191: rec, layer l = blk/64, col-slice cs = blk%64. Round-7 rec
//     + chunk gate (cdone[l][c] == 64) + outs published sc1 in the deferred
//     slot. Drain rule: outs of step t drained by S4(t) => flag >= t+2
//     implies outs_t visible. After the loop: one more flag = T+2 (all outs
//     drained by the final S4).
//   Blocks 192..255: 64 GEMM workers, static task order key = 2c+3l
//     (topological: every wait's prerequisite task strictly precedes it ->
//     deadlock-free). Task (l,c): [l>0] wait bar[l-1] >= min((c+1)*32+l+1,
//     T[l-1]+2); [c>=2] wait bar[l] >= (c-1)*32 (ring slot free). Then 2
//     tiles of 128x192 (6-wave: 2x3 wave grid, all 384 threads compute),
//     sc1 G stores, syncthreads drain, ONE atomicAdd signal.
// ---------------------------------------------------------------------------
__global__ __launch_bounds__(384, 1) void k_mega(MegaArgs A) {
    __shared__ __attribute__((aligned(16))) char smem[98304];
    const int tid = threadIdx.x, blk = blockIdx.x;
    const int lane = tid & 63, w = tid >> 6;
    const int quad = lane >> 4, lr = lane & 15;

    if (blk >= 192) {
        // ------------------------- worker role ----------------------------
        bf16* lsA = (bf16*)smem;             // 128 x 64 bf16 (16KB)
        bf16* lsW = (bf16*)(smem + 16384);   // 192 x 64 bf16 (24KB)
        const int wid = blk - 192;
        const int wr = w / 3, wc = w - wr * 3;   // 2x3 wave grid
        for (int key = 0; key <= 36; ++key) {
            for (int l = 0; l < 3; ++l) {
                int rem = key - 3 * l;
                if (rem < 0 || (rem & 1)) continue;
                int c = rem >> 1;
                if (c >= 16) continue;
                // ---- waits ----
                if (l > 0) {
                    uint need = (uint)((c + 1) * 32 + l + 1);
                    uint cap = (uint)(A.T[l - 1] + 2);
                    if (need > cap) need = cap;
                    if (tid < 64) {
                        const uint* fp = A.bar[l - 1] + (uint)tid * FLAG_STRIDE;
                        while (__hip_atomic_load(fp, AG) < need)
                            __builtin_amdgcn_s_sleep(2);
                    }
                }
                if (c >= 2) {
                    uint need = (uint)((c - 1) * 32);
                    if (tid < 64) {
                        const uint* fp = A.bar[l] + (uint)tid * FLAG_STRIDE;
                        while (__hip_atomic_load(fp, AG) < need)
                            __builtin_amdgcn_s_sleep(2);
                    }
                }
                __syncthreads();
                // ---- compute 2 tiles of 128x192 ----
                const bf16* xsP = A.xs[l];
                const bf16* msP = A.ms[l];
                const bf16* wxP = A.wXh[l];
                const bf16* wnP = A.wNh[l];
                const float* b1 = A.bxh[l];
                const float* b2 = A.bnh[l];
                float* Gs = A.G[l] + (size_t)(c & 1) * CHUNKF;
                const int Mst = A.T[l] * 32;
                const int nks[2] = {A.nkx[l], 4};
                const bf16* Aps[2] = {xsP, msP};
                const int ldas[2] = {A.lda[l], 256};
                const bf16* Wps[2] = {wxP, wnP};
#pragma unroll 1
                for (int half = 0; half < 2; ++half) {
                    int tl = wid * 2 + half;       // 0..127
                    int by = tl >> 4, bx = tl & 15;
                    int m0g = c * 1024 + by * 128;
                    int n0 = bx * 192;
                    floatx4 acc[4][4] = {};
                    for (int ph = 0; ph < 2; ++ph) {
                        const int nk = nks[ph];
                        const bf16* Ap = Aps[ph];
                        const int ldap = ldas[ph];
                        const bf16* Wp = Wps[ph];
                        const int ldw = nk * 64;
                        for (int kb = 0; kb < nk; ++kb) {
                            const bf16* Ab = Ap + (size_t)m0g * ldap + (size_t)kb * 64;
                            const bf16* Wb = Wp + (size_t)n0 * ldw + (size_t)kb * 64;
#pragma unroll
                            for (int r = 0; r < 7; ++r) {
                                int idx = tid + r * 384;
                                if (r < 6 || idx < 2560) {
                                    if (idx < 1024) {
                                        int m = idx >> 3, q = idx & 7;
                                        const bf16* src = Ab + (size_t)m * ldap + ((q ^ (m & 7)) << 3);
                                        __builtin_amdgcn_global_load_lds(
                                            (const gvoid*)src, (lvoid*)(lsA + idx * 8), 16, 0, 0);
                                    } else {
                                        int j2 = idx - 1024;
                                        int m = j2 >> 3, q = j2 & 7;
                                        const bf16* src = Wb + (size_t)m * ldw + ((q ^ (m & 7)) << 3);
                                        __builtin_amdgcn_global_load_lds(
                                            (const gvoid*)src, (lvoid*)(lsW + j2 * 8), 16, 0, 0);
                                    }
                                }
                            }
                            __syncthreads();
#pragma unroll
                            for (int s = 0; s < 2; ++s) {
                                bf16x8 af[4], bfr[4];
#pragma unroll
                                for (int i = 0; i < 4; ++i) {
                                    int kc = s * 4 + quad;
                                    int mA = wr * 64 + i * 16 + lr;
                                    af[i] = *(const bf16x8*)(lsA + mA * 64 + ((kc ^ (mA & 7)) << 3));
                                    int nB = wc * 64 + i * 16 + lr;
                                    bfr[i] = *(const bf16x8*)(lsW + nB * 64 + ((kc ^ (nB & 7)) << 3));
                                }
#pragma unroll
                                for (int i = 0; i < 4; ++i)
#pragma unroll
                                    for (int j = 0; j < 4; ++j)
                                        acc[i][j] = MFMA16(af[i], bfr[j], acc[i][j]);
                            }
                            __syncthreads();
                        }
                    }
#pragma unroll
                    for (int j = 0; j < 4; ++j) {
                        int col = n0 + wc * 64 + j * 16 + lr;
                        float bs = b1[col] + b2[col];
#pragma unroll
                        for (int i = 0; i < 4; ++i) {
                            int rowb = m0g + wr * 64 + i * 16 + quad * 4;
#pragma unroll
                            for (int r = 0; r < 4; ++r) {
                                int row = rowb + r;
                                if (row < Mst) {
                                    float v = acc[i][j][r] + bs;
                                    __hip_atomic_store(
                                        (uint*)(Gs + (size_t)(row - c * 1024) * 3072 + col),
                                        __float_as_uint(v), AG);
                                }
                            }
                        }
                    }
                }
                __syncthreads();  // drain this block's sc1 G stores
                if (tid == 0) atomicAdd(A.cdone[l] + c, 1u);
            }
        }
        return;
    }

    // ----------------------------- rec role -------------------------------
    const int l = blk >> 6, cs = blk & 63;
    const int T = A.T[l];
    bf16* hT = (bf16*)smem;
    float* gh = (float*)(smem + 66560);
    const int mi = (w >= 3) ? 1 : 0, ni = w - mi * 3;

    const float* Whh = A.Whh[l];
    const float* bhh = A.bhh[l];
    bf16* outs = A.outs[l];
    bf16* h01 = A.h01[l];
    float* Gb = A.G[l];
    uint* bar = A.bar[l];
    const uint* cdone = A.cdone[l];

    const float* wrow = Whh + ((size_t)ni * 1024 + cs * 16 + lr) * 1024 + quad * 8;
    bf16x8 breg[32];
#pragma unroll
    for (int kt = 0; kt < 32; ++kt) {
        const floatx4* p = (const floatx4*)(wrow + kt * 32);
        floatx4 lo = p[0], hi = p[1];
        bf16x8 b;
        b[0] = (bf16)lo.x; b[1] = (bf16)lo.y; b[2] = (bf16)lo.z; b[3] = (bf16)lo.w;
        b[4] = (bf16)hi.x; b[5] = (bf16)hi.y; b[6] = (bf16)hi.z; b[7] = (bf16)hi.w;
        breg[kt] = b;
    }

    const int eb = tid >> 3;
    const int ec = (tid & 7) * 2;
    const int ecg = cs * 16 + ec;

    float bhr0 = 0.f, bhr1 = 0.f, bhi0 = 0.f, bhi1 = 0.f, bhn0 = 0.f, bhn1 = 0.f;
    if (tid < 256) {
        bhr0 = bhh[ecg];        bhr1 = bhh[ecg + 1];
        bhi0 = bhh[1024 + ecg]; bhi1 = bhh[1024 + ecg + 1];
        bhn0 = bhh[2048 + ecg]; bhn1 = bhh[2048 + ecg + 1];
    }
    float hreg0 = 0.f, hreg1 = 0.f;  // h0 = 0
    floatx2 pAr = {0.f, 0.f}, pAi = {0.f, 0.f}, pAn = {0.f, 0.f};
    floatx2 pBr = {0.f, 0.f}, pBi = {0.f, 0.f}, pBn = {0.f, 0.f};
    uint* myflag = bar + (uint)cs * FLAG_STRIDE;

    for (int t = 0; t < T; ++t) {
        if ((t & 31) == 0) {
            const uint* cd = cdone + (t >> 5);
            if (tid < 64) {
                while (__hip_atomic_load(cd, AG) < (uint)NB_W)
                    __builtin_amdgcn_s_sleep(1);
            }
            __syncthreads();
            if (tid < 256) {
                const float* Grow = Gb + (size_t)((t >> 5) & 1) * CHUNKF
                                      + ((size_t)(t & 31) * 32 + eb) * 3072 + ecg;
                pAr = ldg2(Grow);
                pAi = ldg2(Grow + 1024);
                pAn = ldg2(Grow + 2048);
            }
        }

        if (t == 0) {
            for (int i = tid; i < 4096; i += 384) {
                int row = i >> 7, q = i & 127;
                uintx4 z = {0u, 0u, 0u, 0u};
                *(uintx4*)(hT + row * HSTR + q * 8) = z;
            }
        } else {
            const bf16* hb = h01 + (size_t)(t & 1) * (32 * 1024);
            u64 s0[11], s1[11];
#pragma unroll
            for (int r = 0; r < 11; ++r) {
                int ci = tid + r * 384;
                if (r < 10 || ci < 4096) {
                    const u64* src = (const u64*)(hb + (size_t)ci * 8);
                    s0[r] = __hip_atomic_load(src, AG);
                    s1[r] = __hip_atomic_load(src + 1, AG);
                }
            }
#pragma unroll
            for (int r = 0; r < 11; ++r) {
                int ci = tid + r * 384;
                if (r < 10 || ci < 4096) {
                    int row = ci >> 7, q = ci & 127;
                    u64x2 v; v.x = s0[r]; v.y = s1[r];
                    *(u64x2*)(hT + row * HSTR + q * 8) = v;
                }
            }
        }
        __syncthreads();  // S1

        floatx4 acc0 = {0.f, 0.f, 0.f, 0.f}, acc1 = {0.f, 0.f, 0.f, 0.f};
        const bf16* aB = hT + (mi * 16 + lr) * HSTR + quad * 8;
#pragma unroll
        for (int kt = 0; kt < 32; kt += 2) {
            bf16x8 a0 = *(const bf16x8*)(aB + kt * 32);
            acc0 = MFMA16(a0, breg[kt], acc0);
            bf16x8 a1 = *(const bf16x8*)(aB + kt * 32 + 32);
            acc1 = MFMA16(a1, breg[kt + 1], acc1);
        }
        floatx4 acc = acc0 + acc1;
#pragma unroll
        for (int r = 0; r < 4; ++r)
            gh[(ni * 32 + mi * 16 + quad * 4 + r) * 17 + lr] = acc[r];
        __syncthreads();  // S2

        uint pku = 0u;
        if (tid < 256) {
            float ghr0 = gh[eb * 17 + ec]            + bhr0;
            float ghr1 = gh[eb * 17 + ec + 1]        + bhr1;
            float ghi0 = gh[(32 + eb) * 17 + ec]     + bhi0;
            float ghi1 = gh[(32 + eb) * 17 + ec + 1] + bhi1;
            float ghn0 = gh[(64 + eb) * 17 + ec]     + bhn0;
            float ghn1 = gh[(64 + eb) * 17 + ec + 1] + bhn1;
            float rg0 = 1.f / (1.f + __expf(-(pAr.x + ghr0)));
            float rg1 = 1.f / (1.f + __expf(-(pAr.y + ghr1)));
            float ig0 = 1.f / (1.f + __expf(-(pAi.x + ghi0)));
            float ig1 = 1.f / (1.f + __expf(-(pAi.y + ghi1)));
            float pre0 = pAn.x + rg0 * ghn0;
            float pre1 = pAn.y + rg1 * ghn1;
            float e20 = __expf(2.f * pre0);
            float e21 = __expf(2.f * pre1);
            float ng0 = 1.f - 2.f / (e20 + 1.f);
            float ng1 = 1.f - 2.f / (e21 + 1.f);
            hreg0 = ng0 + ig0 * (hreg0 - ng0);
            hreg1 = ng1 + ig1 * (hreg1 - ng1);
            union { bf16 h[2]; uint u; } pk;
            pk.h[0] = (bf16)hreg0;
            pk.h[1] = (bf16)hreg1;
            pku = pk.u;
            __hip_atomic_store((uint*)(h01 + (size_t)((t + 1) & 1) * (32 * 1024)
                                       + (size_t)eb * 1024 + ecg), pku, AG);
        }
        __syncthreads();  // S3: drains h publish

        if (tid == 0) __hip_atomic_store(myflag, (uint)(t + 1), AG);

        // Deferred: outs publish (sc1 -> workers read cross-XCD) + G prefetch.
        // Drained by S4 => flag >= t+2 implies outs_t visible (worker rule).
        if (tid < 256) {
            if (t + 1 < T && ((t + 1) & 31) != 0) {
                const float* Grow = Gb + (size_t)((t >> 5) & 1) * CHUNKF
                                      + ((size_t)((t + 1) & 31) * 32 + eb) * 3072 + ecg;
                pBr = ldg2(Grow);
                pBi = ldg2(Grow + 1024);
                pBn = ldg2(Grow + 2048);
            }
            __hip_atomic_store((uint*)(outs + ((size_t)t * 32 + eb) * 1024 + ecg),
                               pku, AG);
        }
        if (t + 1 < T && tid < 64) {
            const uint* fp = bar + (uint)tid * FLAG_STRIDE;
            while (__hip_atomic_load(fp, AG) < (uint)(t + 1))
                __builtin_amdgcn_s_sleep(1);
        }
        __syncthreads();  // S4: drains deferred outs store

        pAr = pBr; pAi = pBi; pAn = pBn;
    }

    // Final: S4 of the last step already drained the last outs store.
    if (tid == 0) __hip_atomic_store(myflag, (uint)(T + 2), AG);
    if (tid < 256) {
        floatx2 h; h.x = hreg0; h.y = hreg1;
        *(floatx2*)(A.hid[l] + (size_t)eb * 1024 + ecg) = h;
    }
}

// ---------------------------------------------------------------------------
extern "C" void kernel_launch(void* const* d_in, const int* in_sizes, int n_in,
                              void* d_out, int out_size, void* d_ws, size_t ws_size,
                              hipStream_t stream) {
    const float* inp  = (const float*)d_in[0];
    const float* Wxh0 = (const float*)d_in[1];
    const float* bxh0 = (const float*)d_in[2];
    const float* Whh0 = (const float*)d_in[3];
    const float* bhh0 = (const float*)d_in[4];
    const float* Wnh0 = (const float*)d_in[5];
    const float* bnh0 = (const float*)d_in[6];
    const float* Wxh1 = (const float*)d_in[7];
    const float* bxh1 = (const float*)d_in[8];
    const float* Whh1 = (const float*)d_in[9];
    const float* bhh1 = (const float*)d_in[10];
    const float* Wnh1 = (const float*)d_in[11];
    const float* bnh1 = (const float*)d_in[12];
    const float* Wxh2 = (const float*)d_in[13];
    const float* bxh2 = (const float*)d_in[14];
    const float* Whh2 = (const float*)d_in[15];
    const float* bhh2 = (const float*)d_in[16];
    const float* Wnh2 = (const float*)d_in[17];
    const float* bnh2 = (const float*)d_in[18];
    const float* Wout = (const float*)d_in[19];
    const float* bout = (const float*)d_in[20];
    float* out = (float*)d_out;

    char* ws = (char*)d_ws;
    size_t o = 0;
    auto take = [&](size_t bytes) {
        o = (o + 255) & ~(size_t)255;
        char* p = ws + o;
        o += bytes;
        return p;
    };
    const size_t RP = 16512;
    bf16* xT    = (bf16*)take(RP * 256 * 2);
    bf16* ms1   = (bf16*)take(RP * 256 * 2);
    bf16* ms2   = (bf16*)take(RP * 256 * 2);
    bf16* outs0 = (bf16*)take(RP * 1024 * 2);
    bf16* outs1 = (bf16*)take(RP * 1024 * 2);
    bf16* outs2 = (bf16*)take(RP * 1024 * 2);
    bf16* h01   = (bf16*)take((size_t)3 * 2 * 32 * 1024 * 2);
    float* hf   = (float*)take((size_t)32 * 1024 * 4);
    uint* bar   = (uint*)take((size_t)(3 * NB_REC * FLAG_STRIDE + 64) * 4);
    bf16* wXh0 = (bf16*)take((size_t)3072 * 256 * 2);
    bf16* wXh1 = (bf16*)take((size_t)3072 * 1024 * 2);
    bf16* wXh2 = (bf16*)take((size_t)3072 * 1024 * 2);
    bf16* wNh0 = (bf16*)take((size_t)3072 * 256 * 2);
    bf16* wNh1 = (bf16*)take((size_t)3072 * 256 * 2);
    bf16* wNh2 = (bf16*)take((size_t)3072 * 256 * 2);
    bf16* wOut = (bf16*)take((size_t)256 * 1024 * 2);
    o = (o + 255) & ~(size_t)255;
    float* G = (float*)(ws + o);
    size_t availG = (ws_size > o) ? (ws_size - o) : 0;
    const int use_mega = availG >= (size_t)6 * CHUNKF * 4;
    (void)in_sizes; (void)n_in; (void)out_size;

    const size_t o0 = 0, o1 = (size_t)512 * 32 * 256, o2 = o1 + (size_t)511 * 32 * 256;
    const size_t ohid = o2 + (size_t)509 * 32 * 256;

    auto cvt = [&](const float* s, bf16* d, int n) {
        k_cvt<<<(n + 255) / 256, 256, 0, stream>>>(s, d, n);
    };
    cvt(Wout, wOut, 256 * 1024);
    cvt(Wxh0, wXh0, 3072 * 256);
    cvt(Wxh1, wXh1, 3072 * 1024);
    cvt(Wxh2, wXh2, 3072 * 1024);
    cvt(Wnh0, wNh0, 3072 * 256);
    cvt(Wnh1, wNh1, 3072 * 256);
    cvt(Wnh2, wNh2, 3072 * 256);
    k_prep<<<16384, 256, 0, stream>>>(inp, xT, bar);
    k_movmean<<<511 * 32, 256, 0, stream>>>(xT, ms1, 2);
    k_movmean<<<509 * 32, 256, 0, stream>>>(xT, ms2, 4);

    if (use_mega) {
        MegaArgs A;
        const bf16* xsA[3]  = {xT, outs0 + (size_t)32 * 1024, outs1 + (size_t)64 * 1024};
        const int ldaA[3]   = {256, 1024, 1024};
        const bf16* wXhA[3] = {wXh0, wXh1, wXh2};
        const int nkxA[3]   = {4, 16, 16};
        const bf16* msA[3]  = {xT, ms1, ms2};
        const bf16* wNhA[3] = {wNh0, wNh1, wNh2};
        const float* bxhA[3] = {bxh0, bxh1, bxh2};
        const float* bnhA[3] = {bnh0, bnh1, bnh2};
        const float* WhhA[3] = {Whh0, Whh1, Whh2};
        const float* bhhA[3] = {bhh0, bhh1, bhh2};
        bf16* outsA[3] = {outs0, outs1, outs2};
        const int TA[3] = {512, 511, 509};
        for (int l = 0; l < 3; ++l) {
            A.xs[l] = xsA[l];   A.lda[l] = ldaA[l];
            A.wXh[l] = wXhA[l]; A.nkx[l] = nkxA[l];
            A.ms[l] = msA[l];   A.wNh[l] = wNhA[l];
            A.bxh[l] = bxhA[l]; A.bnh[l] = bnhA[l];
            A.Whh[l] = WhhA[l]; A.bhh[l] = bhhA[l];
            A.outs[l] = outsA[l];
            A.hid[l] = out + ohid + (size_t)l * 32768;
            A.G[l] = G + (size_t)l * 2 * CHUNKF;
            A.bar[l] = bar + (size_t)l * NB_REC * FLAG_STRIDE;
            A.cdone[l] = bar + 3 * NB_REC * FLAG_STRIDE + 16 * l;
            A.h01[l] = h01 + (size_t)l * 2 * 32 * 1024;
            A.T[l] = TA[l];
        }
        k_mega<<<256, 384, 0, stream>>>(A);
    } else {
        // Serial fallback: round-7 proven path, CT adapted to remaining ws.
        int CT = (int)(availG / ((size_t)32 * 3072 * 4));
        if (CT > 512) CT = 512;
        if (CT < 4) CT = 4;
        auto run_layer = [&](const bf16* xs, int ldx, const bf16* wXh, int nkx,
                             const bf16* ms, const bf16* wNh,
                             const float* bxh, const float* bnh,
                             const float* Whh, const float* bhh,
                             bf16* outs, float* hid, int T, int layer) {
            uint base = 0;
            for (int t0 = 0; t0 < T; t0 += CT) {
                int ct = (T - t0 < CT) ? (T - t0) : CT;
                int gy = (ct * 32 + 127) / 128;
                k_gemm<<<dim3(24, gy), 256, 0, stream>>>(
                    xs + (size_t)t0 * 32 * ldx, ldx, wXh, nkx,
                    ms + (size_t)t0 * 32 * 256, 256, wNh, 4,
                    bxh, bnh, G, (bf16*)nullptr, 3072, ct * 32);
                k_rec<<<NB_REC, 384, 0, stream>>>(
                    G, Whh, bhh, outs + (size_t)t0 * 32 * 1024, h01, hf, hid,
                    bar + (size_t)NB_REC * FLAG_STRIDE * layer, ct,
                    (t0 == 0) ? 1 : 0, (t0 + ct >= T) ? 1 : 0, base + 1);
                base += (uint)ct + 1;
            }
        };
        run_layer(xT, 256, wXh0, 4, xT, wNh0, bxh0, bnh0, Whh0, bhh0,
                  outs0, out + ohid, 512, 0);
        run_layer(outs0 + (size_t)32 * 1024, 1024, wXh1, 16, ms1, wNh1,
                  bxh1, bnh1, Whh1, bhh1, outs1, out + ohid + 32768, 511, 1);
        run_layer(outs1 + (size_t)64 * 1024, 1024, wXh2, 16, ms2, wNh2,
                  bxh2, bnh2, Whh2, bhh2, outs2, out + ohid + 65536, 509, 2);
    }

    k_gemm<<<dim3(2, 128), 256, 0, stream>>>(outs0, 1024, wOut, 16,
                                             nullptr, 0, nullptr, 0, bout, nullptr,
                                             out + o0, nullptr, 256, 16384);
    k_gemm<<<dim3(2, 128), 256, 0, stream>>>(outs1, 1024, wOut, 16,
                                             nullptr, 0, nullptr, 0, bout, nullptr,
                                             out + o1, nullptr, 256, 16352);
    k_gemm<<<dim3(2, 128), 256, 0, stream>>>(outs2, 1024, wOut, 16,
                                             nullptr, 0, nullptr, 0, bout, nullptr,
                                             out + o2, nullptr, 256, 16288);
}